// Round 7
// baseline (249.815 us; speedup 1.0000x reference)
//
#include <hip/hip_runtime.h>

// ---------------------------------------------------------------------------
// MultiQueryAttention: out = softmax_causal((xWq+bq)(xWk+bk)^T * scale) (xWv+bv) Wo + bo
// B=2, S=2048, HIDDEN=2048, HEADS=16 (multi-query: 1 KV head), HEAD_DIM=128
// R6: 256-wide ring-4 slab-pipelined GEMMs (T2 swizzle + T3 phases + T4 counted
//     vmcnt + T5 setprio), 512 threads, 128KB LDS, 1 block/CU. Attn unchanged.
// ---------------------------------------------------------------------------

#define HIDDEN 2048
#define NHEADS 16
#define HDIM 128
#define BATCH 2
#define SEQ 2048
// SCALE_QK * log2(e): softmax computed in base-2 (exp2), exactly equivalent.
#define SCALE_L2E 0.1275258653864023f

typedef __attribute__((ext_vector_type(8))) short bfrag;   // 8 bf16 (4 VGPRs)
typedef __attribute__((ext_vector_type(4))) float facc;    // MFMA accumulator

__device__ __forceinline__ unsigned short f2bf(float f) {  // f32 -> bf16 RNE
  unsigned int u = __float_as_uint(f);
  u += 0x7fffu + ((u >> 16) & 1u);
  return (unsigned short)(u >> 16);
}

// HW packed f32x2 -> bf16x2 (RNE); no builtin on gfx950, inline asm (T12).
__device__ __forceinline__ unsigned int cvt_pk_bf16(float lo, float hi) {
  unsigned int r;
  asm("v_cvt_pk_bf16_f32 %0, %1, %2" : "=v"(r) : "v"(lo), "v"(hi));
  return r;
}

// async global->LDS, 16B per lane. LDS dest is WAVE-UNIFORM base (+lane*16 by HW).
__device__ __forceinline__ void gl_lds16(const void* g, void* l) {
  __builtin_amdgcn_global_load_lds(
      (const __attribute__((address_space(1))) void*)g,
      (__attribute__((address_space(3))) void*)l, 16, 0, 0);
}

// ---------------------------------------------------------------------------
// x f32 -> bf16 (vectorized, HW cvt_pk)
__global__ __launch_bounds__(256) void cvt_bf16(const float* __restrict__ in,
                                                unsigned int* __restrict__ out, int n4) {
  int i = blockIdx.x * 256 + threadIdx.x;
  if (i >= n4) return;
  float4 v = ((const float4*)in)[i];
  uint2 o = {cvt_pk_bf16(v.x, v.y), cvt_pk_bf16(v.z, v.w)};
  ((uint2*)out)[i] = o;
}

// Two weights per launch (blockIdx.z picks): W [K][N] f32 -> WT [N][K] bf16.
__global__ __launch_bounds__(256) void transpose_cvt2(const float* __restrict__ W0,
                                                      short* __restrict__ T0,
                                                      const float* __restrict__ W1,
                                                      short* __restrict__ T1,
                                                      int K, int N) {
  const float* W = blockIdx.z ? W1 : W0;
  short* WT = blockIdx.z ? T1 : T0;
  __shared__ float t[32][33];
  int tx = threadIdx.x & 31, ty = threadIdx.x >> 5;
  int n0 = blockIdx.x * 32, k0 = blockIdx.y * 32;
#pragma unroll
  for (int j = 0; j < 4; ++j)
    t[ty + j * 8][tx] = W[(size_t)(k0 + ty + j * 8) * N + n0 + tx];
  __syncthreads();
#pragma unroll
  for (int j = 0; j < 4; ++j)
    WT[(size_t)(n0 + ty + j * 8) * K + k0 + tx] = (short)f2bf(t[tx][ty + j * 8]);
}

// ---------------------------------------------------------------------------
// 256x256 ring-4 slab GEMM. 512 threads = 8 waves (2M x 4N); per-wave C =
// 128x64. K-slab = 32 (one MFMA k-step); ring of 4 slabs (A+B = 32KB/slab).
// Window t = K-tile of 64 = slabs {2t,2t+1}, 4 phases (slab x M-half qm).
// Stage schedule: ph1 A(2t+3), ph2 B(2t+3), ph3 A(2t+4), ph4 B(2t+4).
//   - slot(2t+3)=slot(2t-1): last read window t-1 ph4 (barrier-ordered) -> safe.
//   - slot(2t+4)=slot(2t):   last read ph2 of this window -> issue at ph3 safe.
// Waits (counted, per derivation): end-ph2 vmcnt(8) [covers slab 2t+1],
// end-ph4 vmcnt(8) [covers slab 2t+2]; tail: vmcnt(4)/vmcnt(0).
// LDS chunk swizzle: chunk c of row r stored at slot c ^ ((r>>1)&3)
//   -> ds_read_b128 2-way only; global source XOR stays inside each 64B row.

#define SBAR() __builtin_amdgcn_s_barrier()
#define LGKM0()                                        \
  do {                                                 \
    asm volatile("s_waitcnt lgkmcnt(0)" ::: "memory"); \
    __builtin_amdgcn_sched_barrier(0);                 \
  } while (0)
#define WAIT_VM(n) asm volatile("s_waitcnt vmcnt(" #n ")" ::: "memory")

#define STG_A(s)                                                            \
  _Pragma("unroll") for (int it_ = 0; it_ < 2; ++it_) {                     \
    int rb_ = w * 32 + it_ * 16;                                            \
    gl_lds16(Ag + (size_t)(m0 + rb_ + (l >> 2)) * Kdim + (s) * 32 +         \
                 (((l & 3) ^ ((l >> 3) & 3)) << 3),                         \
             &As[(s) & 3][rb_ * 32]);                                       \
  }
#define STG_B(s)                                                            \
  _Pragma("unroll") for (int it_ = 0; it_ < 2; ++it_) {                     \
    int rb_ = w * 32 + it_ * 16;                                            \
    gl_lds16(Bg + (size_t)(n0 + rb_ + (l >> 2)) * Kdim + (s) * 32 +         \
                 (((l & 3) ^ ((l >> 3) & 3)) << 3),                         \
             &Bs[(s) & 3][rb_ * 32]);                                       \
  }
#define RD_A(slot_, qm_)                                                    \
  _Pragma("unroll") for (int mt = 0; mt < 4; ++mt) {                        \
    int r_ = wm * 128 + (qm_) * 64 + mt * 16 + l15;                         \
    af[mt] = *(const bfrag*)&As[slot_][r_ * 32 + ((l4 ^ ((r_ >> 1) & 3)) << 3)]; \
  }
#define RD_B(slot_)                                                         \
  _Pragma("unroll") for (int nt = 0; nt < 4; ++nt) {                        \
    int r_ = wn * 64 + nt * 16 + l15;                                       \
    bf[nt] = *(const bfrag*)&Bs[slot_][r_ * 32 + ((l4 ^ ((r_ >> 1) & 3)) << 3)]; \
  }
#define MFMA16(qm_)                                                         \
  __builtin_amdgcn_s_setprio(1);                                            \
  _Pragma("unroll") for (int mt = 0; mt < 4; ++mt)                          \
      _Pragma("unroll") for (int nt = 0; nt < 4; ++nt)                      \
          acc[qm_][mt][nt] = __builtin_amdgcn_mfma_f32_16x16x32_bf16(       \
              af[mt], bf[nt], acc[qm_][mt][nt], 0, 0, 0);                   \
  __builtin_amdgcn_s_setprio(0);

#define GEMM256_MAIN(Ag, Bg, Kdim)                                          \
  facc acc[2][4][4] = {};                                                   \
  const int NS = (Kdim) >> 5;                                               \
  const int NT = NS >> 1;                                                   \
  STG_A(0); STG_B(0); STG_A(1); STG_B(1); STG_A(2); STG_B(2);               \
  WAIT_VM(8);                                                               \
  SBAR();                                                                   \
  for (int t = 0; t < NT; ++t) {                                            \
    const int sl0 = (2 * t) & 3, sl1 = (2 * t + 1) & 3;                     \
    bfrag af[4], bf[4];                                                     \
    /* phase 1: slab 2t, qm=0 */                                            \
    RD_A(sl0, 0); RD_B(sl0);                                                \
    if (2 * t + 3 < NS) { STG_A(2 * t + 3); }                               \
    SBAR(); LGKM0(); MFMA16(0);                                             \
    SBAR();                                                                 \
    /* phase 2: slab 2t, qm=1 (B reused) */                                 \
    RD_A(sl0, 1);                                                           \
    if (2 * t + 3 < NS) { STG_B(2 * t + 3); }                               \
    SBAR(); LGKM0(); MFMA16(1);                                             \
    if (t < NT - 1) { WAIT_VM(8); } else { WAIT_VM(0); }                    \
    SBAR();                                                                 \
    /* phase 3: slab 2t+1, qm=0 */                                          \
    RD_A(sl1, 0); RD_B(sl1);                                                \
    if (2 * t + 4 < NS) { STG_A(2 * t + 4); }                               \
    SBAR(); LGKM0(); MFMA16(0);                                             \
    SBAR();                                                                 \
    /* phase 4: slab 2t+1, qm=1 */                                          \
    RD_A(sl1, 1);                                                           \
    if (2 * t + 4 < NS) { STG_B(2 * t + 4); }                               \
    SBAR(); LGKM0(); MFMA16(1);                                             \
    if (t < NT - 2) { WAIT_VM(8); }                                         \
    else if (t == NT - 2) { WAIT_VM(4); }                                   \
    SBAR();                                                                 \
  }

// Fused QKV projection: Bg = [Wq^T; Wk^T; Wv^T] (2304 rows). Grid (16, 9).
__global__ __launch_bounds__(512, 1) void gemm_qkv256(const short* __restrict__ Ag,
                                                      const short* __restrict__ Bg,
                                                      const float* __restrict__ bq,
                                                      const float* __restrict__ bk,
                                                      const float* __restrict__ bv,
                                                      unsigned short* __restrict__ Qb,
                                                      unsigned short* __restrict__ Kb,
                                                      unsigned short* __restrict__ Vtb,
                                                      int M, int Kdim) {
  __shared__ __align__(16) short As[4][256 * 32];
  __shared__ __align__(16) short Bs[4][256 * 32];
  const int tid = threadIdx.x;
  const int w = tid >> 6, l = tid & 63;
  const int wm = w >> 2, wn = w & 3;
  const int l15 = l & 15, l4 = l >> 4;
  const int m0 = blockIdx.x * 256, n0 = blockIdx.y * 256;
  GEMM256_MAIN(Ag, Bg, Kdim)
#pragma unroll
  for (int qm = 0; qm < 2; ++qm)
#pragma unroll
    for (int mt = 0; mt < 4; ++mt)
#pragma unroll
      for (int nt = 0; nt < 4; ++nt)
#pragma unroll
        for (int r = 0; r < 4; ++r) {
          int row = m0 + wm * 128 + qm * 64 + mt * 16 + l4 * 4 + r;
          int col = n0 + wn * 64 + nt * 16 + l15;
          float v = acc[qm][mt][nt][r];
          if (col < HIDDEN) {
            Qb[(size_t)row * HIDDEN + col] = f2bf(v + bq[col]);
          } else if (col < HIDDEN + HDIM) {
            int lc = col - HIDDEN;
            Kb[(size_t)row * HDIM + lc] = f2bf(v + bk[lc]);
          } else {
            int lc = col - HIDDEN - HDIM;
            Vtb[(size_t)lc * M + row] = f2bf(v + bv[lc]);
          }
        }
}

// O-projection: f32 output. Grid (16, 8).
__global__ __launch_bounds__(512, 1) void gemm_out256(const short* __restrict__ Ag,
                                                      const short* __restrict__ Bg,
                                                      const float* __restrict__ bias,
                                                      float* __restrict__ Cout,
                                                      int M, int N, int Kdim) {
  __shared__ __align__(16) short As[4][256 * 32];
  __shared__ __align__(16) short Bs[4][256 * 32];
  const int tid = threadIdx.x;
  const int w = tid >> 6, l = tid & 63;
  const int wm = w >> 2, wn = w & 3;
  const int l15 = l & 15, l4 = l >> 4;
  const int m0 = blockIdx.x * 256, n0 = blockIdx.y * 256;
  GEMM256_MAIN(Ag, Bg, Kdim)
#pragma unroll
  for (int qm = 0; qm < 2; ++qm)
#pragma unroll
    for (int mt = 0; mt < 4; ++mt)
#pragma unroll
      for (int nt = 0; nt < 4; ++nt)
#pragma unroll
        for (int r = 0; r < 4; ++r) {
          int row = m0 + wm * 128 + qm * 64 + mt * 16 + l4 * 4 + r;
          int col = n0 + wn * 64 + nt * 16 + l15;
          Cout[(size_t)row * N + col] = acc[qm][mt][nt][r] + bias[col];
        }
}

// ---------------------------------------------------------------------------
// Flash attention, swapped QK^T, causal-paired blocks, 4 waves x 16 q-rows
// (QBLK=64). Grid: (16, HEADS, B) = 512 blocks, 256 threads, 72KB LDS ->
// 2 blocks/CU. Pass 0: q-tile x; pass 1: q-tile 31-x -> 33 KV-tiles each.
__global__ __launch_bounds__(256, 2) void attn_kernel(const short* __restrict__ Q,
                                                      const short* __restrict__ Kg,
                                                      const short* __restrict__ Vt,
                                                      unsigned short* __restrict__ O) {
  __shared__ __align__(16) short Kl[2][64 * 128];  // [buf][key][d] swizzled
  __shared__ __align__(16) short Vl[2][128 * 64];  // [buf][d][key] swizzled
  __shared__ __align__(16) char Pl[4][2048];       // per-wave 16q x 64k bf16 swizzled
  const int tid = threadIdx.x;
  const int w = tid >> 6, l = tid & 63;
  const int l15 = l & 15, l4 = l >> 4;
  const int h = blockIdx.y, b = blockIdx.z;

#define STAGE_KV(buf, t)                                                            \
  do {                                                                              \
    const int kv0_ = (t) << 6;                                                      \
    _Pragma("unroll") for (int it = 0; it < 4; ++it) {                              \
      int bc = (w * 4 + it) * 64;                                                   \
      int C = bc + l;                                                               \
      int key = C >> 4, c = C & 15;                                                 \
      gl_lds16(Kg + (size_t)(b * SEQ + kv0_ + key) * HDIM + ((c ^ (key & 7)) << 3), \
               &Kl[buf][bc * 8]);                                                   \
    }                                                                               \
    _Pragma("unroll") for (int it = 0; it < 4; ++it) {                              \
      int bc = (w * 4 + it) * 64;                                                   \
      int C = bc + l;                                                               \
      int d = C >> 3, c = C & 7;                                                    \
      gl_lds16(Vt + (size_t)d * (BATCH * SEQ) + b * SEQ + kv0_ + ((c ^ (d & 7)) << 3), \
               &Vl[buf][bc * 8]);                                                   \
    }                                                                               \
  } while (0)

  for (int pass = 0; pass < 2; ++pass) {
    const int qtile = (pass == 0) ? (int)blockIdx.x : 31 - (int)blockIdx.x;
    const int q0 = qtile * 64;
    const int qw = q0 + w * 16;  // this wave's 16 q-rows [qw, qw+16)

    // Q fragments (B-operand: col=q=l15, k contiguous): 4 k-chunks of 32
    bfrag aq[4];
#pragma unroll
    for (int kk = 0; kk < 4; ++kk)
      aq[kk] = *(const bfrag*)(Q + (size_t)(b * SEQ + qw + l15) * HIDDEN +
                               h * HDIM + kk * 32 + l4 * 8);

    facc accO[8] = {};
    float mrow = -INFINITY, lrow = 0.f;
    const int nkv = qtile + 1;

    STAGE_KV(0, 0);
    __syncthreads();

    for (int t = 0; t < nkv; ++t) {
      const int cur = t & 1;
      if (t + 1 < nkv) STAGE_KV(cur ^ 1, t + 1);
      const int kv0 = t << 6;

      // S^T = K * Q^T : A-frag = K (row=key=l15), B-frag = Q (col=q=l15).
      facc sac[4] = {};
      __builtin_amdgcn_s_setprio(1);
#pragma unroll
      for (int kk = 0; kk < 4; ++kk) {
        int c = kk * 4 + l4;
#pragma unroll
        for (int kt = 0; kt < 4; ++kt) {
          int key = kt * 16 + l15;
          bfrag ak = *(const bfrag*)&Kl[cur][key * 128 + ((c ^ (key & 7)) << 3)];
          sac[kt] = __builtin_amdgcn_mfma_f32_16x16x32_bf16(ak, aq[kk], sac[kt], 0, 0, 0);
        }
      }
      __builtin_amdgcn_s_setprio(0);

      // online softmax (base-2): lane holds 16 S values for q = l15
      const int qg = qw + l15;
      const bool needmask = (kv0 + 63 > qw);
      float p[4][4];
      float mt = -INFINITY;
#pragma unroll
      for (int kt = 0; kt < 4; ++kt)
#pragma unroll
        for (int r = 0; r < 4; ++r) {
          float v = sac[kt][r] * SCALE_L2E;
          if (needmask) {
            int keyg = kv0 + kt * 16 + l4 * 4 + r;
            v = (keyg <= qg) ? v : -INFINITY;
          }
          p[kt][r] = v;
          mt = fmaxf(mt, v);
        }
      mt = fmaxf(mt, __shfl_xor(mt, 16));
      mt = fmaxf(mt, __shfl_xor(mt, 32));
      float mn = fmaxf(mrow, mt);
      float f = exp2f(mrow - mn);
      mrow = mn;
      float ps = 0.f;
#pragma unroll
      for (int kt = 0; kt < 4; ++kt)
#pragma unroll
        for (int r = 0; r < 4; ++r) {
          p[kt][r] = exp2f(p[kt][r] - mn);
          ps += p[kt][r];
        }
      ps += __shfl_xor(ps, 16);
      ps += __shfl_xor(ps, 32);
      lrow = lrow * f + ps;
      float fr[4];
#pragma unroll
      for (int r = 0; r < 4; ++r) fr[r] = __shfl(f, l4 * 4 + r);

      // pack P^T -> P[q][key] bf16 in per-wave LDS (swizzled rows), HW cvt_pk
      char* pw = &Pl[w][0];
#pragma unroll
      for (int kt = 0; kt < 4; ++kt)
#pragma unroll
        for (int rp = 0; rp < 2; ++rp) {
          unsigned int u = cvt_pk_bf16(p[kt][2 * rp], p[kt][2 * rp + 1]);
          int byte = (l15 * 128 + (kt * 16 + l4 * 4 + 2 * rp) * 2) ^ ((l15 & 7) << 4);
          *(unsigned int*)(pw + byte) = u;
        }
      // rescale O accumulator (rows q = l4*4+r)
#pragma unroll
      for (int nt = 0; nt < 8; ++nt)
#pragma unroll
        for (int r = 0; r < 4; ++r) accO[nt][r] *= fr[r];

      // PV: A = P[q][key] (row=q=l15), B = V^T row d (col=d=l15, k=key contig)
      __builtin_amdgcn_s_setprio(1);
#pragma unroll
      for (int kc = 0; kc < 2; ++kc) {
        bfrag pa = *(const bfrag*)(&Pl[w][0] +
                                   ((l15 * 128 + (kc * 32 + l4 * 8) * 2) ^ ((l15 & 7) << 4)));
#pragma unroll
        for (int nt = 0; nt < 8; ++nt) {
          int d = nt * 16 + l15;
          int cslot = (kc * 4 + l4) ^ (d & 7);
          bfrag bv = *(const bfrag*)&Vl[cur][d * 64 + (cslot << 3)];
          accO[nt] = __builtin_amdgcn_mfma_f32_16x16x32_bf16(pa, bv, accO[nt], 0, 0, 0);
        }
      }
      __builtin_amdgcn_s_setprio(0);
      __syncthreads();
    }

    // epilogue: O rows q = l4*4+r, cols d = nt*16+l15
    float inv = 1.f / lrow;
#pragma unroll
    for (int r = 0; r < 4; ++r) {
      float invr = __shfl(inv, l4 * 4 + r);
      int row = qw + l4 * 4 + r;
#pragma unroll
      for (int nt = 0; nt < 8; ++nt)
        O[(size_t)(b * SEQ + row) * HIDDEN + h * HDIM + nt * 16 + l15] =
            f2bf(accO[nt][r] * invr);
    }
  }
#undef STAGE_KV
}

// ---------------------------------------------------------------------------
extern "C" void kernel_launch(void* const* d_in, const int* in_sizes, int n_in,
                              void* d_out, int out_size, void* d_ws, size_t ws_size,
                              hipStream_t stream) {
  const float* x = (const float*)d_in[0];
  // d_in[1] = mask (causal, applied analytically)
  const float* Wq = (const float*)d_in[2];
  const float* bq = (const float*)d_in[3];
  const float* Wk = (const float*)d_in[4];
  const float* bk = (const float*)d_in[5];
  const float* Wv = (const float*)d_in[6];
  const float* bv = (const float*)d_in[7];
  const float* Wo = (const float*)d_in[8];
  const float* bo = (const float*)d_in[9];
  float* out = (float*)d_out;

  const size_t MS = (size_t)BATCH * SEQ;  // 4096
  char* ws = (char*)d_ws;
  short* xb = (short*)ws;      ws += MS * HIDDEN * 2;
  short* WqkvT = (short*)ws;   ws += (size_t)(HIDDEN + 2 * HDIM) * HIDDEN * 2;  // 2304 rows
  short* WoT = (short*)ws;     ws += (size_t)HIDDEN * HIDDEN * 2;
  short* Qb = (short*)ws;      ws += MS * HIDDEN * 2;
  short* Kb = (short*)ws;      ws += MS * HDIM * 2;
  short* Vtb = (short*)ws;     ws += (size_t)HDIM * MS * 2;
  short* Ab = (short*)ws;      ws += MS * HIDDEN * 2;

  cvt_bf16<<<(int)(MS * HIDDEN / 4 / 256), 256, 0, stream>>>(
      x, (unsigned int*)xb, (int)(MS * HIDDEN / 4));
  transpose_cvt2<<<dim3(HIDDEN / 32, HIDDEN / 32, 2), 256, 0, stream>>>(
      Wq, WqkvT, Wo, WoT, HIDDEN, HIDDEN);
  transpose_cvt2<<<dim3(HDIM / 32, HIDDEN / 32, 2), 256, 0, stream>>>(
      Wk, WqkvT + (size_t)HIDDEN * HIDDEN, Wv, WqkvT + (size_t)(HIDDEN + HDIM) * HIDDEN,
      HIDDEN, HDIM);

  gemm_qkv256<<<dim3(16, 9), 512, 0, stream>>>(xb, WqkvT, bq, bk, bv,
                                               (unsigned short*)Qb, (unsigned short*)Kb,
                                               (unsigned short*)Vtb, (int)MS, HIDDEN);

  attn_kernel<<<dim3(16, NHEADS, BATCH), 256, 0, stream>>>(Qb, Kb, Vtb,
                                                           (unsigned short*)Ab);

  gemm_out256<<<dim3(16, 8), 512, 0, stream>>>(Ab, WoT, bo, out, (int)MS, HIDDEN, HIDDEN);
}

// Round 8
// 211.620 us; speedup vs baseline: 1.1805x; 1.1805x over previous
//
#include <hip/hip_runtime.h>

// ---------------------------------------------------------------------------
// MultiQueryAttention: out = softmax_causal((xWq+bq)(xWk+bk)^T * scale) (xWv+bv) Wo + bo
// B=2, S=2048, HIDDEN=2048, HEADS=16 (multi-query: 1 KV head), HEAD_DIM=128
// R7: GEMMs -> 8 waves/block (512 thr) on 128x128 dbuf tile: 2x resident waves
//     per CU (occupancy was the binding constraint, not schedule depth).
//     Attn unchanged (R5). 256-ring experiment reverted.
// ---------------------------------------------------------------------------

#define HIDDEN 2048
#define NHEADS 16
#define HDIM 128
#define BATCH 2
#define SEQ 2048
// SCALE_QK * log2(e): softmax computed in base-2 (exp2), exactly equivalent.
#define SCALE_L2E 0.1275258653864023f

typedef __attribute__((ext_vector_type(8))) short bfrag;   // 8 bf16 (4 VGPRs)
typedef __attribute__((ext_vector_type(4))) float facc;    // MFMA accumulator

__device__ __forceinline__ unsigned short f2bf(float f) {  // f32 -> bf16 RNE
  unsigned int u = __float_as_uint(f);
  u += 0x7fffu + ((u >> 16) & 1u);
  return (unsigned short)(u >> 16);
}

// HW packed f32x2 -> bf16x2 (RNE); no builtin on gfx950, inline asm (T12).
__device__ __forceinline__ unsigned int cvt_pk_bf16(float lo, float hi) {
  unsigned int r;
  asm("v_cvt_pk_bf16_f32 %0, %1, %2" : "=v"(r) : "v"(lo), "v"(hi));
  return r;
}

// async global->LDS, 16B per lane. LDS dest is WAVE-UNIFORM base (+lane*16 by HW).
__device__ __forceinline__ void gl_lds16(const void* g, void* l) {
  __builtin_amdgcn_global_load_lds(
      (const __attribute__((address_space(1))) void*)g,
      (__attribute__((address_space(3))) void*)l, 16, 0, 0);
}

// ---------------------------------------------------------------------------
// x f32 -> bf16 (vectorized, HW cvt_pk)
__global__ __launch_bounds__(256) void cvt_bf16(const float* __restrict__ in,
                                                unsigned int* __restrict__ out, int n4) {
  int i = blockIdx.x * 256 + threadIdx.x;
  if (i >= n4) return;
  float4 v = ((const float4*)in)[i];
  uint2 o = {cvt_pk_bf16(v.x, v.y), cvt_pk_bf16(v.z, v.w)};
  ((uint2*)out)[i] = o;
}

// Two weights per launch (blockIdx.z picks): W [K][N] f32 -> WT [N][K] bf16.
__global__ __launch_bounds__(256) void transpose_cvt2(const float* __restrict__ W0,
                                                      short* __restrict__ T0,
                                                      const float* __restrict__ W1,
                                                      short* __restrict__ T1,
                                                      int K, int N) {
  const float* W = blockIdx.z ? W1 : W0;
  short* WT = blockIdx.z ? T1 : T0;
  __shared__ float t[32][33];
  int tx = threadIdx.x & 31, ty = threadIdx.x >> 5;
  int n0 = blockIdx.x * 32, k0 = blockIdx.y * 32;
#pragma unroll
  for (int j = 0; j < 4; ++j)
    t[ty + j * 8][tx] = W[(size_t)(k0 + ty + j * 8) * N + n0 + tx];
  __syncthreads();
#pragma unroll
  for (int j = 0; j < 4; ++j)
    WT[(size_t)(n0 + ty + j * 8) * K + k0 + tx] = (short)f2bf(t[tx][ty + j * 8]);
}

// ---------------------------------------------------------------------------
// 8-wave 128x128 dbuf GEMM. 512 threads = 8 waves in 4M x 2N; per-wave C tile
// 32x64 (acc[2][4] frags). BK=64, double-buffered LDS (64KB -> 2 blocks/CU,
// 16 waves/CU resident). Stage next K-tile before computing current.
#define GEMM_STAGE8(buf, kt, A, BT, Kdim)                                      \
  _Pragma("unroll") for (int it_ = 0; it_ < 2; ++it_) {                        \
    int bc = (w * 2 + it_) * 64;                                               \
    int C = bc + l;                                                            \
    int row = C >> 3, c = C & 7;                                               \
    int gofs = (kt) * 64 + ((c ^ (row & 7)) << 3);                             \
    gl_lds16((A) + (size_t)(m0 + row) * (Kdim) + gofs, &Al[buf][bc * 8]);      \
    gl_lds16((BT) + (size_t)(n0 + row) * (Kdim) + gofs, &Bl[buf][bc * 8]);     \
  }

#define GEMM_PIPE_LOOP8(A, BT, Kdim)                                           \
  facc acc[2][4] = {};                                                         \
  const int nkt = (Kdim) >> 6;                                                 \
  GEMM_STAGE8(0, 0, A, BT, Kdim)                                               \
  __syncthreads();                                                             \
  for (int kt = 0; kt < nkt; ++kt) {                                           \
    const int cur = kt & 1;                                                    \
    if (kt + 1 < nkt) { GEMM_STAGE8(cur ^ 1, kt + 1, A, BT, Kdim) }            \
    __builtin_amdgcn_s_setprio(1);                                             \
    _Pragma("unroll") for (int ks = 0; ks < 2; ++ks) {                         \
      bfrag af[2], bf[4];                                                      \
      _Pragma("unroll") for (int mt = 0; mt < 2; ++mt) {                       \
        int row = wm * 32 + mt * 16 + l15;                                     \
        int c = ks * 4 + l4;                                                   \
        af[mt] = *(const bfrag*)&Al[cur][row * 64 + ((c ^ (row & 7)) << 3)];   \
      }                                                                        \
      _Pragma("unroll") for (int nt = 0; nt < 4; ++nt) {                       \
        int row = wn * 64 + nt * 16 + l15;                                     \
        int c = ks * 4 + l4;                                                   \
        bf[nt] = *(const bfrag*)&Bl[cur][row * 64 + ((c ^ (row & 7)) << 3)];   \
      }                                                                        \
      _Pragma("unroll") for (int mt = 0; mt < 2; ++mt)                         \
          _Pragma("unroll") for (int nt = 0; nt < 4; ++nt)                     \
              acc[mt][nt] = __builtin_amdgcn_mfma_f32_16x16x32_bf16(           \
                  af[mt], bf[nt], acc[mt][nt], 0, 0, 0);                       \
    }                                                                          \
    __builtin_amdgcn_s_setprio(0);                                             \
    __syncthreads();                                                           \
  }

// Fused QKV projection: BT = [Wq^T; Wk^T; Wv^T] (2304 rows). Grid (32, 18).
__global__ __launch_bounds__(512, 4) void gemm_qkv(const short* __restrict__ A,
                                                   const short* __restrict__ BT,
                                                   const float* __restrict__ bq,
                                                   const float* __restrict__ bk,
                                                   const float* __restrict__ bv,
                                                   unsigned short* __restrict__ Qb,
                                                   unsigned short* __restrict__ Kb,
                                                   unsigned short* __restrict__ Vtb,
                                                   int M, int K) {
  __shared__ __align__(16) short Al[2][128 * 64];
  __shared__ __align__(16) short Bl[2][128 * 64];
  const int tid = threadIdx.x;
  const int w = tid >> 6, l = tid & 63;
  const int wm = w >> 1, wn = w & 1;
  const int l15 = l & 15, l4 = l >> 4;
  const int m0 = blockIdx.x * 128, n0 = blockIdx.y * 128;
  GEMM_PIPE_LOOP8(A, BT, K)
#pragma unroll
  for (int mt = 0; mt < 2; ++mt) {
#pragma unroll
    for (int nt = 0; nt < 4; ++nt) {
#pragma unroll
      for (int r = 0; r < 4; ++r) {
        int row = m0 + wm * 32 + mt * 16 + l4 * 4 + r;
        int col = n0 + wn * 64 + nt * 16 + l15;
        float v = acc[mt][nt][r];
        if (col < HIDDEN) {
          Qb[(size_t)row * HIDDEN + col] = f2bf(v + bq[col]);
        } else if (col < HIDDEN + HDIM) {
          int lc = col - HIDDEN;
          Kb[(size_t)row * HDIM + lc] = f2bf(v + bk[lc]);
        } else {
          int lc = col - HIDDEN - HDIM;
          Vtb[(size_t)lc * M + row] = f2bf(v + bv[lc]);
        }
      }
    }
  }
}

// O-projection: f32 output C[row][col] = A*BT^T + bias. Grid (32, 16).
__global__ __launch_bounds__(512, 4) void gemm_out(const short* __restrict__ A,
                                                   const short* __restrict__ BT,
                                                   const float* __restrict__ bias,
                                                   float* __restrict__ Cout,
                                                   int M, int N, int K) {
  __shared__ __align__(16) short Al[2][128 * 64];
  __shared__ __align__(16) short Bl[2][128 * 64];
  const int tid = threadIdx.x;
  const int w = tid >> 6, l = tid & 63;
  const int wm = w >> 1, wn = w & 1;
  const int l15 = l & 15, l4 = l >> 4;
  const int m0 = blockIdx.x * 128, n0 = blockIdx.y * 128;
  GEMM_PIPE_LOOP8(A, BT, K)
#pragma unroll
  for (int mt = 0; mt < 2; ++mt)
#pragma unroll
    for (int nt = 0; nt < 4; ++nt)
#pragma unroll
      for (int r = 0; r < 4; ++r) {
        int row = m0 + wm * 32 + mt * 16 + l4 * 4 + r;
        int col = n0 + wn * 64 + nt * 16 + l15;
        Cout[(size_t)row * N + col] = acc[mt][nt][r] + bias[col];
      }
}

// ---------------------------------------------------------------------------
// Flash attention, swapped QK^T, causal-paired blocks, 4 waves x 16 q-rows
// (QBLK=64). Grid: (16, HEADS, B) = 512 blocks, 256 threads, 72KB LDS ->
// 2 blocks/CU. Pass 0: q-tile x; pass 1: q-tile 31-x -> 33 KV-tiles each.
__global__ __launch_bounds__(256, 2) void attn_kernel(const short* __restrict__ Q,
                                                      const short* __restrict__ Kg,
                                                      const short* __restrict__ Vt,
                                                      unsigned short* __restrict__ O) {
  __shared__ __align__(16) short Kl[2][64 * 128];  // [buf][key][d] swizzled
  __shared__ __align__(16) short Vl[2][128 * 64];  // [buf][d][key] swizzled
  __shared__ __align__(16) char Pl[4][2048];       // per-wave 16q x 64k bf16 swizzled
  const int tid = threadIdx.x;
  const int w = tid >> 6, l = tid & 63;
  const int l15 = l & 15, l4 = l >> 4;
  const int h = blockIdx.y, b = blockIdx.z;

#define STAGE_KV(buf, t)                                                            \
  do {                                                                              \
    const int kv0_ = (t) << 6;                                                      \
    _Pragma("unroll") for (int it = 0; it < 4; ++it) {                              \
      int bc = (w * 4 + it) * 64;                                                   \
      int C = bc + l;                                                               \
      int key = C >> 4, c = C & 15;                                                 \
      gl_lds16(Kg + (size_t)(b * SEQ + kv0_ + key) * HDIM + ((c ^ (key & 7)) << 3), \
               &Kl[buf][bc * 8]);                                                   \
    }                                                                               \
    _Pragma("unroll") for (int it = 0; it < 4; ++it) {                              \
      int bc = (w * 4 + it) * 64;                                                   \
      int C = bc + l;                                                               \
      int d = C >> 3, c = C & 7;                                                    \
      gl_lds16(Vt + (size_t)d * (BATCH * SEQ) + b * SEQ + kv0_ + ((c ^ (d & 7)) << 3), \
               &Vl[buf][bc * 8]);                                                   \
    }                                                                               \
  } while (0)

  for (int pass = 0; pass < 2; ++pass) {
    const int qtile = (pass == 0) ? (int)blockIdx.x : 31 - (int)blockIdx.x;
    const int q0 = qtile * 64;
    const int qw = q0 + w * 16;  // this wave's 16 q-rows [qw, qw+16)

    // Q fragments (B-operand: col=q=l15, k contiguous): 4 k-chunks of 32
    bfrag aq[4];
#pragma unroll
    for (int kk = 0; kk < 4; ++kk)
      aq[kk] = *(const bfrag*)(Q + (size_t)(b * SEQ + qw + l15) * HIDDEN +
                               h * HDIM + kk * 32 + l4 * 8);

    facc accO[8] = {};
    float mrow = -INFINITY, lrow = 0.f;
    const int nkv = qtile + 1;

    STAGE_KV(0, 0);
    __syncthreads();

    for (int t = 0; t < nkv; ++t) {
      const int cur = t & 1;
      if (t + 1 < nkv) STAGE_KV(cur ^ 1, t + 1);
      const int kv0 = t << 6;

      // S^T = K * Q^T : A-frag = K (row=key=l15), B-frag = Q (col=q=l15).
      facc sac[4] = {};
      __builtin_amdgcn_s_setprio(1);
#pragma unroll
      for (int kk = 0; kk < 4; ++kk) {
        int c = kk * 4 + l4;
#pragma unroll
        for (int kt = 0; kt < 4; ++kt) {
          int key = kt * 16 + l15;
          bfrag ak = *(const bfrag*)&Kl[cur][key * 128 + ((c ^ (key & 7)) << 3)];
          sac[kt] = __builtin_amdgcn_mfma_f32_16x16x32_bf16(ak, aq[kk], sac[kt], 0, 0, 0);
        }
      }
      __builtin_amdgcn_s_setprio(0);

      // online softmax (base-2): lane holds 16 S values for q = l15
      const int qg = qw + l15;
      const bool needmask = (kv0 + 63 > qw);
      float p[4][4];
      float mt = -INFINITY;
#pragma unroll
      for (int kt = 0; kt < 4; ++kt)
#pragma unroll
        for (int r = 0; r < 4; ++r) {
          float v = sac[kt][r] * SCALE_L2E;
          if (needmask) {
            int keyg = kv0 + kt * 16 + l4 * 4 + r;
            v = (keyg <= qg) ? v : -INFINITY;
          }
          p[kt][r] = v;
          mt = fmaxf(mt, v);
        }
      mt = fmaxf(mt, __shfl_xor(mt, 16));
      mt = fmaxf(mt, __shfl_xor(mt, 32));
      float mn = fmaxf(mrow, mt);
      float f = exp2f(mrow - mn);
      mrow = mn;
      float ps = 0.f;
#pragma unroll
      for (int kt = 0; kt < 4; ++kt)
#pragma unroll
        for (int r = 0; r < 4; ++r) {
          p[kt][r] = exp2f(p[kt][r] - mn);
          ps += p[kt][r];
        }
      ps += __shfl_xor(ps, 16);
      ps += __shfl_xor(ps, 32);
      lrow = lrow * f + ps;
      float fr[4];
#pragma unroll
      for (int r = 0; r < 4; ++r) fr[r] = __shfl(f, l4 * 4 + r);

      // pack P^T -> P[q][key] bf16 in per-wave LDS (swizzled rows), HW cvt_pk
      char* pw = &Pl[w][0];
#pragma unroll
      for (int kt = 0; kt < 4; ++kt)
#pragma unroll
        for (int rp = 0; rp < 2; ++rp) {
          unsigned int u = cvt_pk_bf16(p[kt][2 * rp], p[kt][2 * rp + 1]);
          int byte = (l15 * 128 + (kt * 16 + l4 * 4 + 2 * rp) * 2) ^ ((l15 & 7) << 4);
          *(unsigned int*)(pw + byte) = u;
        }
      // rescale O accumulator (rows q = l4*4+r)
#pragma unroll
      for (int nt = 0; nt < 8; ++nt)
#pragma unroll
        for (int r = 0; r < 4; ++r) accO[nt][r] *= fr[r];

      // PV: A = P[q][key] (row=q=l15), B = V^T row d (col=d=l15, k=key contig)
      __builtin_amdgcn_s_setprio(1);
#pragma unroll
      for (int kc = 0; kc < 2; ++kc) {
        bfrag pa = *(const bfrag*)(&Pl[w][0] +
                                   ((l15 * 128 + (kc * 32 + l4 * 8) * 2) ^ ((l15 & 7) << 4)));
#pragma unroll
        for (int nt = 0; nt < 8; ++nt) {
          int d = nt * 16 + l15;
          int cslot = (kc * 4 + l4) ^ (d & 7);
          bfrag bv = *(const bfrag*)&Vl[cur][d * 64 + (cslot << 3)];
          accO[nt] = __builtin_amdgcn_mfma_f32_16x16x32_bf16(pa, bv, accO[nt], 0, 0, 0);
        }
      }
      __builtin_amdgcn_s_setprio(0);
      __syncthreads();
    }

    // epilogue: O rows q = l4*4+r, cols d = nt*16+l15
    float inv = 1.f / lrow;
#pragma unroll
    for (int r = 0; r < 4; ++r) {
      float invr = __shfl(inv, l4 * 4 + r);
      int row = qw + l4 * 4 + r;
#pragma unroll
      for (int nt = 0; nt < 8; ++nt)
        O[(size_t)(b * SEQ + row) * HIDDEN + h * HDIM + nt * 16 + l15] =
            f2bf(accO[nt][r] * invr);
    }
  }
#undef STAGE_KV
}

// ---------------------------------------------------------------------------
extern "C" void kernel_launch(void* const* d_in, const int* in_sizes, int n_in,
                              void* d_out, int out_size, void* d_ws, size_t ws_size,
                              hipStream_t stream) {
  const float* x = (const float*)d_in[0];
  // d_in[1] = mask (causal, applied analytically)
  const float* Wq = (const float*)d_in[2];
  const float* bq = (const float*)d_in[3];
  const float* Wk = (const float*)d_in[4];
  const float* bk = (const float*)d_in[5];
  const float* Wv = (const float*)d_in[6];
  const float* bv = (const float*)d_in[7];
  const float* Wo = (const float*)d_in[8];
  const float* bo = (const float*)d_in[9];
  float* out = (float*)d_out;

  const size_t MS = (size_t)BATCH * SEQ;  // 4096
  char* ws = (char*)d_ws;
  short* xb = (short*)ws;      ws += MS * HIDDEN * 2;
  short* WqkvT = (short*)ws;   ws += (size_t)(HIDDEN + 2 * HDIM) * HIDDEN * 2;  // 2304 rows
  short* WoT = (short*)ws;     ws += (size_t)HIDDEN * HIDDEN * 2;
  short* Qb = (short*)ws;      ws += MS * HIDDEN * 2;
  short* Kb = (short*)ws;      ws += MS * HDIM * 2;
  short* Vtb = (short*)ws;     ws += (size_t)HDIM * MS * 2;
  short* Ab = (short*)ws;      ws += MS * HIDDEN * 2;

  cvt_bf16<<<(int)(MS * HIDDEN / 4 / 256), 256, 0, stream>>>(
      x, (unsigned int*)xb, (int)(MS * HIDDEN / 4));
  transpose_cvt2<<<dim3(HIDDEN / 32, HIDDEN / 32, 2), 256, 0, stream>>>(
      Wq, WqkvT, Wo, WoT, HIDDEN, HIDDEN);
  transpose_cvt2<<<dim3(HDIM / 32, HIDDEN / 32, 2), 256, 0, stream>>>(
      Wk, WqkvT + (size_t)HIDDEN * HIDDEN, Wv, WqkvT + (size_t)(HIDDEN + HDIM) * HIDDEN,
      HIDDEN, HDIM);

  gemm_qkv<<<dim3(32, 18), 512, 0, stream>>>(xb, WqkvT, bq, bk, bv,
                                             (unsigned short*)Qb, (unsigned short*)Kb,
                                             (unsigned short*)Vtb, (int)MS, HIDDEN);

  attn_kernel<<<dim3(16, NHEADS, BATCH), 256, 0, stream>>>(Qb, Kb, Vtb,
                                                           (unsigned short*)Ab);

  gemm_out<<<dim3(32, 16), 512, 0, stream>>>(Ab, WoT, bo, out, (int)MS, HIDDEN, HIDDEN);
}